// Round 3
// baseline (1191.183 us; speedup 1.0000x reference)
//
#include <hip/hip_runtime.h>
#include <hip/hip_bf16.h>
#include <math.h>

#define DIM 2048
#define HEADS 16
#define DH 128
#define ATTN_INNER 2048
#define FF_INNER 8192
#define FUSED_N 18688
#define QKV_N 2304          // 2048 q + 128 k + 128 v
#define BATCH 2
#define SEQ 2048
#define ROWS (BATCH*SEQ)    // 4096

typedef __attribute__((ext_vector_type(8))) __bf16 bf16x8;
typedef __attribute__((ext_vector_type(4))) float f32x4;
typedef __attribute__((ext_vector_type(16))) float f32x16;

typedef __attribute__((address_space(1))) void* as1_void;
typedef __attribute__((address_space(3))) void* as3_void;

__device__ __forceinline__ void async16(const void* g, void* l) {
  __builtin_amdgcn_global_load_lds((as1_void)const_cast<void*>(g), (as3_void)l, 16, 0, 0);
}

// ---------------- LayerNorm: fp32 [rows][2048] -> bf16 ----------------
__global__ __launch_bounds__(256) void ln_kernel(const float* __restrict__ x,
                                                 const float* __restrict__ gamma,
                                                 const float* __restrict__ beta,
                                                 __hip_bfloat16* __restrict__ hb) {
  const int row = blockIdx.x;
  const int t = threadIdx.x;
  const float4* x4 = (const float4*)(x + (size_t)row * DIM);
  float4 a = x4[t];
  float4 c = x4[t + 256];
  float s  = a.x + a.y + a.z + a.w + c.x + c.y + c.z + c.w;
  float ss = a.x*a.x + a.y*a.y + a.z*a.z + a.w*a.w +
             c.x*c.x + c.y*c.y + c.z*c.z + c.w*c.w;
  for (int off = 32; off > 0; off >>= 1) {
    s  += __shfl_down(s, off);
    ss += __shfl_down(ss, off);
  }
  __shared__ float red[8];
  int wv = t >> 6, lane = t & 63;
  if (lane == 0) { red[wv] = s; red[wv + 4] = ss; }
  __syncthreads();
  s  = red[0] + red[1] + red[2] + red[3];
  ss = red[4] + red[5] + red[6] + red[7];
  float mu  = s * (1.0f / DIM);
  float var = ss * (1.0f / DIM) - mu * mu;
  float rs  = rsqrtf(var + 1e-5f);
  __hip_bfloat16* o = hb + (size_t)row * DIM;
  float v0[4] = {a.x, a.y, a.z, a.w};
  float v1[4] = {c.x, c.y, c.z, c.w};
#pragma unroll
  for (int i = 0; i < 4; i++) {
    int c0 = t * 4 + i;
    int c1 = 1024 + t * 4 + i;
    o[c0] = __float2bfloat16((v0[i] - mu) * rs * gamma[c0] + beta[c0]);
    o[c1] = __float2bfloat16((v1[i] - mu) * rs * gamma[c1] + beta[c1]);
  }
}

// ------------- transpose + fp32->bf16: src [R][C] -> dst [C][R] -------------
__global__ __launch_bounds__(256) void tcvt_kernel(const float* __restrict__ src,
                                                   __hip_bfloat16* __restrict__ dst,
                                                   int R, int C) {
  __shared__ float tile[64][65];
  const int cb = blockIdx.x * 64, rb = blockIdx.y * 64;
  const int t = threadIdx.x;
  const int lr = t >> 4, lc4 = (t & 15) * 4;
#pragma unroll
  for (int i = 0; i < 4; i++) {
    float4 v = *(const float4*)&src[(size_t)(rb + lr + i * 16) * C + cb + lc4];
    tile[lr + i * 16][lc4 + 0] = v.x;
    tile[lr + i * 16][lc4 + 1] = v.y;
    tile[lr + i * 16][lc4 + 2] = v.z;
    tile[lr + i * 16][lc4 + 3] = v.w;
  }
  __syncthreads();
  const int tcc = t & 31, trc = t >> 5;
#pragma unroll
  for (int i = 0; i < 8; i++) {
    int c = trc + i * 8;
    __hip_bfloat162 pk;
    pk.x = __float2bfloat16(tile[2 * tcc][c]);
    pk.y = __float2bfloat16(tile[2 * tcc + 1][c]);
    *(__hip_bfloat162*)&dst[(size_t)(cb + c) * R + rb + 2 * tcc] = pk;
  }
}

// ------------- transpose bf16: src [R][C] (ld) -> dst [C][R] (ldd) -------------
__global__ __launch_bounds__(256) void tbf16_kernel(const __hip_bfloat16* __restrict__ src, int lds_,
                                                    __hip_bfloat16* __restrict__ dst, int ldd,
                                                    int R, int C) {
  __shared__ __hip_bfloat16 tile[64][65];
  const int cb = blockIdx.x * 64, rb = blockIdx.y * 64;
  const int t = threadIdx.x;
  const int tc = t & 63, tr = t >> 6;
#pragma unroll
  for (int i = 0; i < 16; i++) {
    int r = tr + i * 4;
    tile[r][tc] = src[(size_t)(rb + r) * lds_ + cb + tc];
  }
  __syncthreads();
#pragma unroll
  for (int i = 0; i < 16; i++) {
    int c = tr + i * 4;
    dst[(size_t)(cb + c) * ldd + rb + tc] = tile[tc][c];
  }
}

// ---------------- RoPE in-place on qkv bf16 [4096][2304] ----------------
__global__ __launch_bounds__(256) void rope_kernel(__hip_bfloat16* __restrict__ qkv) {
  const size_t tid = (size_t)blockIdx.x * 256 + threadIdx.x;  // ROWS*17*64 total
  const int d = tid & 63;
  const int u = (tid >> 6) % 17;
  const int row = tid / (17 * 64);
  const int n = row & (SEQ - 1);
  size_t base = (size_t)row * QKV_N + (u < 16 ? u * DH : ATTN_INNER);
  float inv = powf(10000.0f, -(float)d * (1.0f / 64.0f));
  float th = (float)n * inv;
  float cs = cosf(th), sn = sinf(th);
  float a = __bfloat162float(qkv[base + d]);
  float b = __bfloat162float(qkv[base + d + 64]);
  qkv[base + d]      = __float2bfloat16(a * cs - b * sn);
  qkv[base + d + 64] = __float2bfloat16(b * cs + a * sn);
}

// ---------------- qkv GEMM (32x32x16): C[4096][2304] = hb @ wfbt[0:2304]^T
__global__ __launch_bounds__(256, 3) void gemm_qkv(const __hip_bfloat16* __restrict__ A,
                                                   const __hip_bfloat16* __restrict__ Bt,
                                                   __hip_bfloat16* __restrict__ C) {
  __shared__ __hip_bfloat16 As[2][128 * 32];
  __shared__ __hip_bfloat16 Bs[2][128 * 32];
  const int tid = threadIdx.x;
  const int wv = tid >> 6, lane = tid & 63;
  const int l31 = lane & 31, khalf = lane >> 5;
  // GROUP_M swizzle over 18 n-tiles x 32 m-tiles
  const int pid = blockIdx.x;
  const int gid = pid / 144, rem = pid % 144;
  const int m0 = (gid * 8 + (rem % 8)) * 128;
  const int n0 = (rem / 8) * 128;
  const int wm = (wv >> 1) * 64, wn = (wv & 1) * 64;
  const int srow = lane >> 2, scol = (lane & 3) * 8;

  f32x16 acc[2][2] = {};
  for (int k0 = 0; k0 < DIM; k0 += 64) {
#pragma unroll
    for (int h = 0; h < 2; h++)
#pragma unroll
      for (int j = 0; j < 2; j++) {
        int q = wv * 2 + j;
        int row = q * 16 + srow;
        async16(A  + (size_t)(m0 + row) * DIM + k0 + h * 32 + scol, &As[h][q * 512]);
        async16(Bt + (size_t)(n0 + row) * DIM + k0 + h * 32 + scol, &Bs[h][q * 512]);
      }
    __syncthreads();
#pragma unroll
    for (int h = 0; h < 2; h++)
#pragma unroll
      for (int kk = 0; kk < 2; kk++) {
        bf16x8 af[2], bfr[2];
#pragma unroll
        for (int i = 0; i < 2; i++)
          af[i] = *(const bf16x8*)(&As[h][(wm + i * 32 + l31) * 32 + kk * 16 + khalf * 8]);
#pragma unroll
        for (int j = 0; j < 2; j++)
          bfr[j] = *(const bf16x8*)(&Bs[h][(wn + j * 32 + l31) * 32 + kk * 16 + khalf * 8]);
#pragma unroll
        for (int i = 0; i < 2; i++)
#pragma unroll
          for (int j = 0; j < 2; j++)
            acc[i][j] = __builtin_amdgcn_mfma_f32_32x32x16_bf16(af[i], bfr[j], acc[i][j], 0, 0, 0);
      }
    __syncthreads();
  }
#pragma unroll
  for (int i = 0; i < 2; i++)
#pragma unroll
    for (int j = 0; j < 2; j++) {
      int colg = n0 + wn + j * 32 + l31;
#pragma unroll
      for (int r = 0; r < 16; r++) {
        int rowg = m0 + wm + i * 32 + (r & 3) + 4 * khalf + 8 * (r >> 2);
        C[(size_t)rowg * QKV_N + colg] = __float2bfloat16(acc[i][j][r]);
      }
    }
}

// ---------------- merged FF GEMM (32x32x16): gb = silu(h@Wg^T) * (h@Wx^T)
// 1D grid 4096. XCD-aware: xcd owns n-tiles [xcd*16, xcd*16+16), n-fast/m-slow.
__global__ __launch_bounds__(256, 3) void gemm_ff(const __hip_bfloat16* __restrict__ A,
                                                  const __hip_bfloat16* __restrict__ W,
                                                  __hip_bfloat16* __restrict__ G) {
  __shared__ __hip_bfloat16 As[2][128 * 32];
  __shared__ __hip_bfloat16 Bs[2][128 * 32];
  const int tid = threadIdx.x;
  const int wv = tid >> 6, lane = tid & 63;
  const int l31 = lane & 31, khalf = lane >> 5;
  const int pid = blockIdx.x;
  const int xcd = pid & 7, lid = pid >> 3;     // lid in [0,512)
  const int m0 = (lid >> 4) * 128;             // m-tile 0..31
  const int n0 = (xcd * 16 + (lid & 15)) * 64; // n-tile 0..127
  const int wm = (wv >> 1) * 64, wn2 = (wv & 1) * 32;
  const int srow = lane >> 2, scol = (lane & 3) * 8;

  f32x16 ax[2] = {};
  f32x16 ag[2] = {};
  for (int k0 = 0; k0 < DIM; k0 += 64) {
#pragma unroll
    for (int h = 0; h < 2; h++)
#pragma unroll
      for (int j = 0; j < 2; j++) {
        int q = wv * 2 + j;
        int row = q * 16 + srow;
        async16(A + (size_t)(m0 + row) * DIM + k0 + h * 32 + scol, &As[h][q * 512]);
        int wr = (row < 64) ? (QKV_N + n0 + row)
                            : (QKV_N + FF_INNER + n0 + row - 64);
        async16(W + (size_t)wr * DIM + k0 + h * 32 + scol, &Bs[h][q * 512]);
      }
    __syncthreads();
#pragma unroll
    for (int h = 0; h < 2; h++)
#pragma unroll
      for (int kk = 0; kk < 2; kk++) {
        bf16x8 af[2], bx, bg;
#pragma unroll
        for (int i = 0; i < 2; i++)
          af[i] = *(const bf16x8*)(&As[h][(wm + i * 32 + l31) * 32 + kk * 16 + khalf * 8]);
        bx = *(const bf16x8*)(&Bs[h][(wn2 + l31) * 32 + kk * 16 + khalf * 8]);
        bg = *(const bf16x8*)(&Bs[h][(64 + wn2 + l31) * 32 + kk * 16 + khalf * 8]);
#pragma unroll
        for (int i = 0; i < 2; i++) {
          ax[i] = __builtin_amdgcn_mfma_f32_32x32x16_bf16(af[i], bx, ax[i], 0, 0, 0);
          ag[i] = __builtin_amdgcn_mfma_f32_32x32x16_bf16(af[i], bg, ag[i], 0, 0, 0);
        }
      }
    __syncthreads();
  }
#pragma unroll
  for (int i = 0; i < 2; i++) {
    int colg = n0 + wn2 + l31;
#pragma unroll
    for (int r = 0; r < 16; r++) {
      int rowg = m0 + wm + i * 32 + (r & 3) + 4 * khalf + 8 * (r >> 2);
      float xv = ax[i][r];
      float gv = ag[i][r];
      float o = gv / (1.0f + expf(-gv)) * xv;
      G[(size_t)rowg * FF_INNER + colg] = __float2bfloat16(o);
    }
  }
}

// ---------------- merged output GEMM (32x32x16): out = aob@wat^T + gb@wfot^T
// 1D grid 512. XCD-aware quadrants: xcd -> (m-quarter, n-half) 8x8 patch.
__global__ __launch_bounds__(256, 3) void gemm_out(const __hip_bfloat16* __restrict__ A0,
                                                   const __hip_bfloat16* __restrict__ B0,
                                                   const __hip_bfloat16* __restrict__ A1,
                                                   const __hip_bfloat16* __restrict__ B1,
                                                   float* __restrict__ C) {
  __shared__ __hip_bfloat16 As[2][128 * 32];
  __shared__ __hip_bfloat16 Bs[2][128 * 32];
  const int tid = threadIdx.x;
  const int wv = tid >> 6, lane = tid & 63;
  const int l31 = lane & 31, khalf = lane >> 5;
  const int pid = blockIdx.x;
  const int xcd = pid & 7, lid = pid >> 3;          // lid in [0,64)
  const int m0 = ((xcd & 3) * 8 + (lid & 7)) * 128; // 32 m-tiles
  const int n0 = ((xcd >> 2) * 8 + (lid >> 3)) * 128; // 16 n-tiles
  const int wm = (wv >> 1) * 64, wn = (wv & 1) * 64;
  const int srow = lane >> 2, scol = (lane & 3) * 8;

  f32x16 acc[2][2] = {};
  for (int p = 0; p < 2; p++) {
    const __hip_bfloat16* A = p ? A1 : A0;
    const __hip_bfloat16* B = p ? B1 : B0;
    const int K = p ? FF_INNER : ATTN_INNER;
    for (int k0 = 0; k0 < K; k0 += 64) {
#pragma unroll
      for (int h = 0; h < 2; h++)
#pragma unroll
        for (int j = 0; j < 2; j++) {
          int q = wv * 2 + j;
          int row = q * 16 + srow;
          async16(A + (size_t)(m0 + row) * K + k0 + h * 32 + scol, &As[h][q * 512]);
          async16(B + (size_t)(n0 + row) * K + k0 + h * 32 + scol, &Bs[h][q * 512]);
        }
      __syncthreads();
#pragma unroll
      for (int h = 0; h < 2; h++)
#pragma unroll
        for (int kk = 0; kk < 2; kk++) {
          bf16x8 af[2], bfr[2];
#pragma unroll
          for (int i = 0; i < 2; i++)
            af[i] = *(const bf16x8*)(&As[h][(wm + i * 32 + l31) * 32 + kk * 16 + khalf * 8]);
#pragma unroll
          for (int j = 0; j < 2; j++)
            bfr[j] = *(const bf16x8*)(&Bs[h][(wn + j * 32 + l31) * 32 + kk * 16 + khalf * 8]);
#pragma unroll
          for (int i = 0; i < 2; i++)
#pragma unroll
            for (int j = 0; j < 2; j++)
              acc[i][j] = __builtin_amdgcn_mfma_f32_32x32x16_bf16(af[i], bfr[j], acc[i][j], 0, 0, 0);
        }
      __syncthreads();
    }
  }
#pragma unroll
  for (int i = 0; i < 2; i++)
#pragma unroll
    for (int j = 0; j < 2; j++) {
      int colg = n0 + wn + j * 32 + l31;
#pragma unroll
      for (int r = 0; r < 16; r++) {
        int rowg = m0 + wm + i * 32 + (r & 3) + 4 * khalf + 8 * (r >> 2);
        C[(size_t)rowg * DIM + colg] = acc[i][j][r];
      }
    }
}

// ---------------- Flash attention (multi-query, causal) ----------------
__global__ __launch_bounds__(256) void flash_kernel(const __hip_bfloat16* __restrict__ qkv,
                                                    const __hip_bfloat16* __restrict__ vt,
                                                    __hip_bfloat16* __restrict__ aob) {
  __shared__ __hip_bfloat16 Qs[128 * 128];
  __shared__ __hip_bfloat16 Ks[64 * 128];
  __shared__ __hip_bfloat16 Vts[128 * 64];
  __shared__ __hip_bfloat16 Ps[128 * 64];

  const int blk = blockIdx.x;           // qi*32 + bh
  const int bh = blk & 31;
  const int qi = blk >> 5;
  const int qt = (qi & 1) ? (qi >> 1) : (15 - (qi >> 1));
  const int bat = bh >> 4, h = bh & 15;

  const int tid = threadIdx.x;
  const int wv = tid >> 6, lane = tid & 63;
  const int quad = lane >> 4, l15 = lane & 15;
  const float scale = 0.08838834764831845f;

#pragma unroll
  for (int j = 0; j < 8; j++) {
    int is = wv * 8 + j;
    int e = is * 512 + lane * 8;
    int r = e >> 7, c = e & 127;
    async16(qkv + (size_t)(bat * SEQ + qt * 128 + r) * QKV_N + h * DH + c, Qs + is * 512);
  }

  f32x4 oacc[2][8];
#pragma unroll
  for (int i = 0; i < 2; i++)
#pragma unroll
    for (int j = 0; j < 8; j++) oacc[i][j] = (f32x4){0.f, 0.f, 0.f, 0.f};
  float mrow[2][4], lrow[2][4];
#pragma unroll
  for (int i = 0; i < 2; i++)
#pragma unroll
    for (int r = 0; r < 4; r++) { mrow[i][r] = -INFINITY; lrow[i][r] = 0.f; }

  const int jt_max = 2 * qt + 1;
  for (int jt = 0; jt <= jt_max; jt++) {
    __syncthreads();
#pragma unroll
    for (int j = 0; j < 4; j++) {
      int is = wv * 4 + j;
      int e = is * 512 + lane * 8;
      { int r = e >> 7, c = e & 127;
        async16(qkv + (size_t)(bat * SEQ + jt * 64 + r) * QKV_N + ATTN_INNER + c, Ks + is * 512); }
      { int d = e >> 6, jc = e & 63;
        async16(vt + (size_t)d * ROWS + bat * SEQ + jt * 64 + jc, Vts + is * 512); }
    }
    __syncthreads();

    f32x4 sacc[2][4];
#pragma unroll
    for (int i = 0; i < 2; i++)
#pragma unroll
      for (int j = 0; j < 4; j++) sacc[i][j] = (f32x4){0.f, 0.f, 0.f, 0.f};
#pragma unroll
    for (int kq = 0; kq < 4; kq++) {
      bf16x8 qa[2], kb[4];
#pragma unroll
      for (int i = 0; i < 2; i++)
        qa[i] = *(const bf16x8*)(Qs + (wv * 32 + i * 16 + l15) * 128 + kq * 32 + quad * 8);
#pragma unroll
      for (int j = 0; j < 4; j++)
        kb[j] = *(const bf16x8*)(Ks + (j * 16 + l15) * 128 + kq * 32 + quad * 8);
#pragma unroll
      for (int i = 0; i < 2; i++)
#pragma unroll
        for (int j = 0; j < 4; j++)
          sacc[i][j] = __builtin_amdgcn_mfma_f32_16x16x32_bf16(qa[i], kb[j], sacc[i][j], 0, 0, 0);
    }

#pragma unroll
    for (int i = 0; i < 2; i++) {
#pragma unroll
      for (int r = 0; r < 4; r++) {
        int row_g = qt * 128 + wv * 32 + i * 16 + quad * 4 + r;
        float mt = -INFINITY;
#pragma unroll
        for (int j = 0; j < 4; j++) {
          int col_g = jt * 64 + j * 16 + l15;
          float sv = sacc[i][j][r] * scale;
          if (col_g > row_g) sv = -INFINITY;
          sacc[i][j][r] = sv;
          mt = fmaxf(mt, sv);
        }
#pragma unroll
        for (int off = 1; off < 16; off <<= 1) mt = fmaxf(mt, __shfl_xor(mt, off));
        float mn = fmaxf(mrow[i][r], mt);
        float al = expf(mrow[i][r] - mn);
        float rs = 0.f;
#pragma unroll
        for (int j = 0; j < 4; j++) {
          float p = expf(sacc[i][j][r] - mn);
          sacc[i][j][r] = p;
          rs += p;
        }
#pragma unroll
        for (int off = 1; off < 16; off <<= 1) rs += __shfl_xor(rs, off);
        lrow[i][r] = lrow[i][r] * al + rs;
        mrow[i][r] = mn;
#pragma unroll
        for (int i2 = 0; i2 < 8; i2++) oacc[i][i2][r] *= al;
      }
    }

#pragma unroll
    for (int i = 0; i < 2; i++)
#pragma unroll
      for (int j = 0; j < 4; j++)
#pragma unroll
        for (int r = 0; r < 4; r++)
          Ps[(wv * 32 + i * 16 + quad * 4 + r) * 64 + j * 16 + l15] =
              __float2bfloat16(sacc[i][j][r]);
    __syncthreads();

#pragma unroll
    for (int kp = 0; kp < 2; kp++) {
      bf16x8 pa[2], vb[8];
#pragma unroll
      for (int i = 0; i < 2; i++)
        pa[i] = *(const bf16x8*)(Ps + (wv * 32 + i * 16 + l15) * 64 + kp * 32 + quad * 8);
#pragma unroll
      for (int i2 = 0; i2 < 8; i2++)
        vb[i2] = *(const bf16x8*)(Vts + (i2 * 16 + l15) * 64 + kp * 32 + quad * 8);
#pragma unroll
      for (int i = 0; i < 2; i++)
#pragma unroll
        for (int i2 = 0; i2 < 8; i2++)
          oacc[i][i2] = __builtin_amdgcn_mfma_f32_16x16x32_bf16(pa[i], vb[i2], oacc[i][i2], 0, 0, 0);
    }
  }

#pragma unroll
  for (int i = 0; i < 2; i++)
#pragma unroll
    for (int r = 0; r < 4; r++) {
      float inv = 1.0f / lrow[i][r];
      int row_g = bat * SEQ + qt * 128 + wv * 32 + i * 16 + quad * 4 + r;
#pragma unroll
      for (int i2 = 0; i2 < 8; i2++)
        aob[(size_t)row_g * ATTN_INNER + h * DH + i2 * 16 + l15] =
            __float2bfloat16(oacc[i][i2][r] * inv);
    }
}

// ---------------- host ----------------
extern "C" void kernel_launch(void* const* d_in, const int* in_sizes, int n_in,
                              void* d_out, int out_size, void* d_ws, size_t ws_size,
                              hipStream_t stream) {
  const float* x       = (const float*)d_in[0];
  const float* gamma   = (const float*)d_in[1];
  const float* beta    = (const float*)d_in[2];
  const float* w_fused = (const float*)d_in[3];
  const float* w_attn  = (const float*)d_in[4];
  const float* w_ff    = (const float*)d_in[5];
  float* out = (float*)d_out;
  char* ws = (char*)d_ws;

  size_t off = 0;
  auto alloc = [&](size_t bytes) {
    size_t o = off;
    off += (bytes + 255) & ~(size_t)255;
    return o;
  };
  __hip_bfloat16* hb   = (__hip_bfloat16*)(ws + alloc((size_t)ROWS * DIM * 2));
  __hip_bfloat16* wfbt = (__hip_bfloat16*)(ws + alloc((size_t)FUSED_N * DIM * 2));
  __hip_bfloat16* qkvb = (__hip_bfloat16*)(ws + alloc((size_t)ROWS * QKV_N * 2));
  __hip_bfloat16* gb   = (__hip_bfloat16*)(ws + alloc((size_t)ROWS * FF_INNER * 2));
  __hip_bfloat16* wat  = (__hip_bfloat16*)(ws + alloc((size_t)DIM * ATTN_INNER * 2));
  __hip_bfloat16* wfot = (__hip_bfloat16*)(ws + alloc((size_t)DIM * FF_INNER * 2));
  __hip_bfloat16* vt   = (__hip_bfloat16*)(ws + alloc((size_t)DH * ROWS * 2));
  __hip_bfloat16* aob  = (__hip_bfloat16*)(ws + alloc((size_t)ROWS * ATTN_INNER * 2));

  ln_kernel<<<ROWS, 256, 0, stream>>>(x, gamma, beta, hb);

  tcvt_kernel<<<dim3(FUSED_N / 64, DIM / 64), 256, 0, stream>>>(w_fused, wfbt, DIM, FUSED_N);
  tcvt_kernel<<<dim3(DIM / 64, ATTN_INNER / 64), 256, 0, stream>>>(w_attn, wat, ATTN_INNER, DIM);
  tcvt_kernel<<<dim3(DIM / 64, FF_INNER / 64), 256, 0, stream>>>(w_ff, wfot, FF_INNER, DIM);

  gemm_qkv<<<(QKV_N / 128) * (ROWS / 128), 256, 0, stream>>>(hb, wfbt, qkvb);

  rope_kernel<<<(ROWS * 17 * 64) / 256, 256, 0, stream>>>(qkvb);

  tbf16_kernel<<<dim3(DH / 64, ROWS / 64), 256, 0, stream>>>(qkvb + ATTN_INNER + DH, QKV_N, vt, ROWS, ROWS, DH);

  flash_kernel<<<512, 256, 0, stream>>>(qkvb, vt, aob);

  gemm_ff<<<(FF_INNER / 64) * (ROWS / 128), 256, 0, stream>>>(hb, wfbt, gb);

  gemm_out<<<(DIM / 128) * (ROWS / 128), 256, 0, stream>>>(aob, wat, gb, wfot, out);

  (void)in_sizes; (void)n_in; (void)out_size; (void)ws_size;
}

// Round 4
// 1153.167 us; speedup vs baseline: 1.0330x; 1.0330x over previous
//
#include <hip/hip_runtime.h>
#include <hip/hip_bf16.h>
#include <math.h>

#define DIM 2048
#define HEADS 16
#define DH 128
#define ATTN_INNER 2048
#define FF_INNER 8192
#define FUSED_N 18688
#define QKV_N 2304          // 2048 q + 128 k + 128 v
#define BATCH 2
#define SEQ 2048
#define ROWS (BATCH*SEQ)    // 4096

typedef __attribute__((ext_vector_type(8))) __bf16 bf16x8;
typedef __attribute__((ext_vector_type(4))) float f32x4;
typedef __attribute__((ext_vector_type(16))) float f32x16;

typedef __attribute__((address_space(1))) void* as1_void;
typedef __attribute__((address_space(3))) void* as3_void;

__device__ __forceinline__ void async16(const void* g, void* l) {
  __builtin_amdgcn_global_load_lds((as1_void)const_cast<void*>(g), (as3_void)l, 16, 0, 0);
}

// ---------------- LayerNorm: fp32 [rows][2048] -> bf16 ----------------
__global__ __launch_bounds__(256) void ln_kernel(const float* __restrict__ x,
                                                 const float* __restrict__ gamma,
                                                 const float* __restrict__ beta,
                                                 __hip_bfloat16* __restrict__ hb) {
  const int row = blockIdx.x;
  const int t = threadIdx.x;
  const float4* x4 = (const float4*)(x + (size_t)row * DIM);
  float4 a = x4[t];
  float4 c = x4[t + 256];
  float s  = a.x + a.y + a.z + a.w + c.x + c.y + c.z + c.w;
  float ss = a.x*a.x + a.y*a.y + a.z*a.z + a.w*a.w +
             c.x*c.x + c.y*c.y + c.z*c.z + c.w*c.w;
  for (int off = 32; off > 0; off >>= 1) {
    s  += __shfl_down(s, off);
    ss += __shfl_down(ss, off);
  }
  __shared__ float red[8];
  int wv = t >> 6, lane = t & 63;
  if (lane == 0) { red[wv] = s; red[wv + 4] = ss; }
  __syncthreads();
  s  = red[0] + red[1] + red[2] + red[3];
  ss = red[4] + red[5] + red[6] + red[7];
  float mu  = s * (1.0f / DIM);
  float var = ss * (1.0f / DIM) - mu * mu;
  float rs  = rsqrtf(var + 1e-5f);
  __hip_bfloat16* o = hb + (size_t)row * DIM;
  float v0[4] = {a.x, a.y, a.z, a.w};
  float v1[4] = {c.x, c.y, c.z, c.w};
#pragma unroll
  for (int i = 0; i < 4; i++) {
    int c0 = t * 4 + i;
    int c1 = 1024 + t * 4 + i;
    o[c0] = __float2bfloat16((v0[i] - mu) * rs * gamma[c0] + beta[c0]);
    o[c1] = __float2bfloat16((v1[i] - mu) * rs * gamma[c1] + beta[c1]);
  }
}

// ------------- transpose + fp32->bf16: src [R][C] -> dst [C][R] -------------
__global__ __launch_bounds__(256) void tcvt_kernel(const float* __restrict__ src,
                                                   __hip_bfloat16* __restrict__ dst,
                                                   int R, int C) {
  __shared__ float tile[64][65];
  const int cb = blockIdx.x * 64, rb = blockIdx.y * 64;
  const int t = threadIdx.x;
  const int lr = t >> 4, lc4 = (t & 15) * 4;
#pragma unroll
  for (int i = 0; i < 4; i++) {
    float4 v = *(const float4*)&src[(size_t)(rb + lr + i * 16) * C + cb + lc4];
    tile[lr + i * 16][lc4 + 0] = v.x;
    tile[lr + i * 16][lc4 + 1] = v.y;
    tile[lr + i * 16][lc4 + 2] = v.z;
    tile[lr + i * 16][lc4 + 3] = v.w;
  }
  __syncthreads();
  const int tcc = t & 31, trc = t >> 5;
#pragma unroll
  for (int i = 0; i < 8; i++) {
    int c = trc + i * 8;
    __hip_bfloat162 pk;
    pk.x = __float2bfloat16(tile[2 * tcc][c]);
    pk.y = __float2bfloat16(tile[2 * tcc + 1][c]);
    *(__hip_bfloat162*)&dst[(size_t)(cb + c) * R + rb + 2 * tcc] = pk;
  }
}

// ------------- transpose bf16: src [R][C] (ld) -> dst [C][R] (ldd) -------------
__global__ __launch_bounds__(256) void tbf16_kernel(const __hip_bfloat16* __restrict__ src, int lds_,
                                                    __hip_bfloat16* __restrict__ dst, int ldd,
                                                    int R, int C) {
  __shared__ __hip_bfloat16 tile[64][65];
  const int cb = blockIdx.x * 64, rb = blockIdx.y * 64;
  const int t = threadIdx.x;
  const int tc = t & 63, tr = t >> 6;
#pragma unroll
  for (int i = 0; i < 16; i++) {
    int r = tr + i * 4;
    tile[r][tc] = src[(size_t)(rb + r) * lds_ + cb + tc];
  }
  __syncthreads();
#pragma unroll
  for (int i = 0; i < 16; i++) {
    int c = tr + i * 4;
    dst[(size_t)(cb + c) * ldd + rb + tc] = tile[tc][c];
  }
}

// ---------------- RoPE in-place on qkv bf16 [4096][2304] ----------------
__global__ __launch_bounds__(256) void rope_kernel(__hip_bfloat16* __restrict__ qkv) {
  const size_t tid = (size_t)blockIdx.x * 256 + threadIdx.x;  // ROWS*17*64 total
  const int d = tid & 63;
  const int u = (tid >> 6) % 17;
  const int row = tid / (17 * 64);
  const int n = row & (SEQ - 1);
  size_t base = (size_t)row * QKV_N + (u < 16 ? u * DH : ATTN_INNER);
  float inv = powf(10000.0f, -(float)d * (1.0f / 64.0f));
  float th = (float)n * inv;
  float cs = cosf(th), sn = sinf(th);
  float a = __bfloat162float(qkv[base + d]);
  float b = __bfloat162float(qkv[base + d + 64]);
  qkv[base + d]      = __float2bfloat16(a * cs - b * sn);
  qkv[base + d + 64] = __float2bfloat16(b * cs + a * sn);
}

// XOR-swizzled LDS tile, 128 rows x 32 cols bf16 (64 B row = 4 x 16B blocks).
// Element (row, block b) lives at physical block b ^ (row & 3).
// Staging: lane's LDS slot is fixed (row = q*16 + lane>>2, phys block = lane&3);
// pick global col = ((lane&3) ^ (row&3)) * 8 -> same 64B row per 4-lane cluster.

// ---------------- qkv GEMM (32x32x16): C[4096][2304] = hb @ wfbt[0:2304]^T
// XCD m-band swizzle: each xcd owns 4 m-tiles (2 MB A-band, fits per-XCD L2).
__global__ __launch_bounds__(256, 3) void gemm_qkv(const __hip_bfloat16* __restrict__ A,
                                                   const __hip_bfloat16* __restrict__ Bt,
                                                   __hip_bfloat16* __restrict__ C) {
  __shared__ __hip_bfloat16 As[2][128 * 32];
  __shared__ __hip_bfloat16 Bs[2][128 * 32];
  const int tid = threadIdx.x;
  const int wv = tid >> 6, lane = tid & 63;
  const int l31 = lane & 31, khalf = lane >> 5;
  const int rx = l31 & 3;                         // xor key for fragment reads
  const int pid = blockIdx.x;                     // grid 576
  const int xcd = pid & 7, lid = pid >> 3;        // lid in [0,72)
  const int m0 = (xcd * 4 + (lid & 3)) * 128;
  const int n0 = (lid >> 2) * 128;
  const int wm = (wv >> 1) * 64, wn = (wv & 1) * 64;
  const int srow = lane >> 2;
  const int scol = (((lane & 3) ^ (srow & 3)) * 8);

  f32x16 acc[2][2] = {};
  for (int k0 = 0; k0 < DIM; k0 += 64) {
#pragma unroll
    for (int h = 0; h < 2; h++)
#pragma unroll
      for (int j = 0; j < 2; j++) {
        int q = wv * 2 + j;
        int row = q * 16 + srow;
        async16(A  + (size_t)(m0 + row) * DIM + k0 + h * 32 + scol, &As[h][q * 512]);
        async16(Bt + (size_t)(n0 + row) * DIM + k0 + h * 32 + scol, &Bs[h][q * 512]);
      }
    __syncthreads();
#pragma unroll
    for (int h = 0; h < 2; h++)
#pragma unroll
      for (int kk = 0; kk < 2; kk++) {
        const int blk = (kk * 2 + khalf) ^ rx;
        bf16x8 af[2], bfr[2];
#pragma unroll
        for (int i = 0; i < 2; i++)
          af[i] = *(const bf16x8*)(&As[h][(wm + i * 32 + l31) * 32 + blk * 8]);
#pragma unroll
        for (int j = 0; j < 2; j++)
          bfr[j] = *(const bf16x8*)(&Bs[h][(wn + j * 32 + l31) * 32 + blk * 8]);
#pragma unroll
        for (int i = 0; i < 2; i++)
#pragma unroll
          for (int j = 0; j < 2; j++)
            acc[i][j] = __builtin_amdgcn_mfma_f32_32x32x16_bf16(af[i], bfr[j], acc[i][j], 0, 0, 0);
      }
    __syncthreads();
  }
#pragma unroll
  for (int i = 0; i < 2; i++)
#pragma unroll
    for (int j = 0; j < 2; j++) {
      int colg = n0 + wn + j * 32 + l31;
#pragma unroll
      for (int r = 0; r < 16; r++) {
        int rowg = m0 + wm + i * 32 + (r & 3) + 4 * khalf + 8 * (r >> 2);
        C[(size_t)rowg * QKV_N + colg] = __float2bfloat16(acc[i][j][r]);
      }
    }
}

// ---------------- merged FF GEMM (32x32x16): gb = silu(h@Wg^T) * (h@Wx^T)
__global__ __launch_bounds__(256, 3) void gemm_ff(const __hip_bfloat16* __restrict__ A,
                                                  const __hip_bfloat16* __restrict__ W,
                                                  __hip_bfloat16* __restrict__ G) {
  __shared__ __hip_bfloat16 As[2][128 * 32];
  __shared__ __hip_bfloat16 Bs[2][128 * 32];
  const int tid = threadIdx.x;
  const int wv = tid >> 6, lane = tid & 63;
  const int l31 = lane & 31, khalf = lane >> 5;
  const int rx = l31 & 3;
  const int pid = blockIdx.x;                     // grid 4096
  const int xcd = pid & 7, lid = pid >> 3;        // lid in [0,512)
  const int m0 = (xcd * 4 + (lid & 3)) * 128;
  const int n0 = (lid >> 2) * 64;                 // n-tile 0..127
  const int wm = (wv >> 1) * 64, wn2 = (wv & 1) * 32;
  const int srow = lane >> 2;
  const int scol = (((lane & 3) ^ (srow & 3)) * 8);

  f32x16 ax[2] = {};
  f32x16 ag[2] = {};
  for (int k0 = 0; k0 < DIM; k0 += 64) {
#pragma unroll
    for (int h = 0; h < 2; h++)
#pragma unroll
      for (int j = 0; j < 2; j++) {
        int q = wv * 2 + j;
        int row = q * 16 + srow;
        async16(A + (size_t)(m0 + row) * DIM + k0 + h * 32 + scol, &As[h][q * 512]);
        int wr = (row < 64) ? (QKV_N + n0 + row)
                            : (QKV_N + FF_INNER + n0 + row - 64);
        async16(W + (size_t)wr * DIM + k0 + h * 32 + scol, &Bs[h][q * 512]);
      }
    __syncthreads();
#pragma unroll
    for (int h = 0; h < 2; h++)
#pragma unroll
      for (int kk = 0; kk < 2; kk++) {
        const int blk = (kk * 2 + khalf) ^ rx;
        bf16x8 af[2], bx, bg;
#pragma unroll
        for (int i = 0; i < 2; i++)
          af[i] = *(const bf16x8*)(&As[h][(wm + i * 32 + l31) * 32 + blk * 8]);
        bx = *(const bf16x8*)(&Bs[h][(wn2 + l31) * 32 + blk * 8]);
        bg = *(const bf16x8*)(&Bs[h][(64 + wn2 + l31) * 32 + blk * 8]);
#pragma unroll
        for (int i = 0; i < 2; i++) {
          ax[i] = __builtin_amdgcn_mfma_f32_32x32x16_bf16(af[i], bx, ax[i], 0, 0, 0);
          ag[i] = __builtin_amdgcn_mfma_f32_32x32x16_bf16(af[i], bg, ag[i], 0, 0, 0);
        }
      }
    __syncthreads();
  }
#pragma unroll
  for (int i = 0; i < 2; i++) {
    int colg = n0 + wn2 + l31;
#pragma unroll
    for (int r = 0; r < 16; r++) {
      int rowg = m0 + wm + i * 32 + (r & 3) + 4 * khalf + 8 * (r >> 2);
      float xv = ax[i][r];
      float gv = ag[i][r];
      float o = gv / (1.0f + expf(-gv)) * xv;
      G[(size_t)rowg * FF_INNER + colg] = __float2bfloat16(o);
    }
  }
}

// ---------------- merged output GEMM (32x32x16): out = aob@wat^T + gb@wfot^T
__global__ __launch_bounds__(256, 3) void gemm_out(const __hip_bfloat16* __restrict__ A0,
                                                   const __hip_bfloat16* __restrict__ B0,
                                                   const __hip_bfloat16* __restrict__ A1,
                                                   const __hip_bfloat16* __restrict__ B1,
                                                   float* __restrict__ C) {
  __shared__ __hip_bfloat16 As[2][128 * 32];
  __shared__ __hip_bfloat16 Bs[2][128 * 32];
  const int tid = threadIdx.x;
  const int wv = tid >> 6, lane = tid & 63;
  const int l31 = lane & 31, khalf = lane >> 5;
  const int rx = l31 & 3;
  const int pid = blockIdx.x;                     // grid 512
  const int xcd = pid & 7, lid = pid >> 3;        // lid in [0,64)
  const int m0 = (xcd * 4 + (lid & 3)) * 128;
  const int n0 = (lid >> 2) * 128;                // n-tile 0..15
  const int wm = (wv >> 1) * 64, wn = (wv & 1) * 64;
  const int srow = lane >> 2;
  const int scol = (((lane & 3) ^ (srow & 3)) * 8);

  f32x16 acc[2][2] = {};
  for (int p = 0; p < 2; p++) {
    const __hip_bfloat16* A = p ? A1 : A0;
    const __hip_bfloat16* B = p ? B1 : B0;
    const int K = p ? FF_INNER : ATTN_INNER;
    for (int k0 = 0; k0 < K; k0 += 64) {
#pragma unroll
      for (int h = 0; h < 2; h++)
#pragma unroll
        for (int j = 0; j < 2; j++) {
          int q = wv * 2 + j;
          int row = q * 16 + srow;
          async16(A + (size_t)(m0 + row) * K + k0 + h * 32 + scol, &As[h][q * 512]);
          async16(B + (size_t)(n0 + row) * K + k0 + h * 32 + scol, &Bs[h][q * 512]);
        }
      __syncthreads();
#pragma unroll
      for (int h = 0; h < 2; h++)
#pragma unroll
        for (int kk = 0; kk < 2; kk++) {
          const int blk = (kk * 2 + khalf) ^ rx;
          bf16x8 af[2], bfr[2];
#pragma unroll
          for (int i = 0; i < 2; i++)
            af[i] = *(const bf16x8*)(&As[h][(wm + i * 32 + l31) * 32 + blk * 8]);
#pragma unroll
          for (int j = 0; j < 2; j++)
            bfr[j] = *(const bf16x8*)(&Bs[h][(wn + j * 32 + l31) * 32 + blk * 8]);
#pragma unroll
          for (int i = 0; i < 2; i++)
#pragma unroll
            for (int j = 0; j < 2; j++)
              acc[i][j] = __builtin_amdgcn_mfma_f32_32x32x16_bf16(af[i], bfr[j], acc[i][j], 0, 0, 0);
        }
      __syncthreads();
    }
  }
#pragma unroll
  for (int i = 0; i < 2; i++)
#pragma unroll
    for (int j = 0; j < 2; j++) {
      int colg = n0 + wn + j * 32 + l31;
#pragma unroll
      for (int r = 0; r < 16; r++) {
        int rowg = m0 + wm + i * 32 + (r & 3) + 4 * khalf + 8 * (r >> 2);
        C[(size_t)rowg * DIM + colg] = acc[i][j][r];
      }
    }
}

// ---------------- Flash attention (multi-query, causal) ----------------
__global__ __launch_bounds__(256) void flash_kernel(const __hip_bfloat16* __restrict__ qkv,
                                                    const __hip_bfloat16* __restrict__ vt,
                                                    __hip_bfloat16* __restrict__ aob) {
  __shared__ __hip_bfloat16 Qs[128 * 128];
  __shared__ __hip_bfloat16 Ks[64 * 128];
  __shared__ __hip_bfloat16 Vts[128 * 64];
  __shared__ __hip_bfloat16 Ps[128 * 64];

  const int blk = blockIdx.x;           // qi*32 + bh
  const int bh = blk & 31;
  const int qi = blk >> 5;
  const int qt = (qi & 1) ? (qi >> 1) : (15 - (qi >> 1));
  const int bat = bh >> 4, h = bh & 15;

  const int tid = threadIdx.x;
  const int wv = tid >> 6, lane = tid & 63;
  const int quad = lane >> 4, l15 = lane & 15;
  const float scale = 0.08838834764831845f;

#pragma unroll
  for (int j = 0; j < 8; j++) {
    int is = wv * 8 + j;
    int e = is * 512 + lane * 8;
    int r = e >> 7, c = e & 127;
    async16(qkv + (size_t)(bat * SEQ + qt * 128 + r) * QKV_N + h * DH + c, Qs + is * 512);
  }

  f32x4 oacc[2][8];
#pragma unroll
  for (int i = 0; i < 2; i++)
#pragma unroll
    for (int j = 0; j < 8; j++) oacc[i][j] = (f32x4){0.f, 0.f, 0.f, 0.f};
  float mrow[2][4], lrow[2][4];
#pragma unroll
  for (int i = 0; i < 2; i++)
#pragma unroll
    for (int r = 0; r < 4; r++) { mrow[i][r] = -INFINITY; lrow[i][r] = 0.f; }

  const int jt_max = 2 * qt + 1;
  for (int jt = 0; jt <= jt_max; jt++) {
    __syncthreads();
#pragma unroll
    for (int j = 0; j < 4; j++) {
      int is = wv * 4 + j;
      int e = is * 512 + lane * 8;
      { int r = e >> 7, c = e & 127;
        async16(qkv + (size_t)(bat * SEQ + jt * 64 + r) * QKV_N + ATTN_INNER + c, Ks + is * 512); }
      { int d = e >> 6, jc = e & 63;
        async16(vt + (size_t)d * ROWS + bat * SEQ + jt * 64 + jc, Vts + is * 512); }
    }
    __syncthreads();

    f32x4 sacc[2][4];
#pragma unroll
    for (int i = 0; i < 2; i++)
#pragma unroll
      for (int j = 0; j < 4; j++) sacc[i][j] = (f32x4){0.f, 0.f, 0.f, 0.f};
#pragma unroll
    for (int kq = 0; kq < 4; kq++) {
      bf16x8 qa[2], kb[4];
#pragma unroll
      for (int i = 0; i < 2; i++)
        qa[i] = *(const bf16x8*)(Qs + (wv * 32 + i * 16 + l15) * 128 + kq * 32 + quad * 8);
#pragma unroll
      for (int j = 0; j < 4; j++)
        kb[j] = *(const bf16x8*)(Ks + (j * 16 + l15) * 128 + kq * 32 + quad * 8);
#pragma unroll
      for (int i = 0; i < 2; i++)
#pragma unroll
        for (int j = 0; j < 4; j++)
          sacc[i][j] = __builtin_amdgcn_mfma_f32_16x16x32_bf16(qa[i], kb[j], sacc[i][j], 0, 0, 0);
    }

#pragma unroll
    for (int i = 0; i < 2; i++) {
#pragma unroll
      for (int r = 0; r < 4; r++) {
        int row_g = qt * 128 + wv * 32 + i * 16 + quad * 4 + r;
        float mt = -INFINITY;
#pragma unroll
        for (int j = 0; j < 4; j++) {
          int col_g = jt * 64 + j * 16 + l15;
          float sv = sacc[i][j][r] * scale;
          if (col_g > row_g) sv = -INFINITY;
          sacc[i][j][r] = sv;
          mt = fmaxf(mt, sv);
        }
#pragma unroll
        for (int off = 1; off < 16; off <<= 1) mt = fmaxf(mt, __shfl_xor(mt, off));
        float mn = fmaxf(mrow[i][r], mt);
        float al = expf(mrow[i][r] - mn);
        float rs = 0.f;
#pragma unroll
        for (int j = 0; j < 4; j++) {
          float p = expf(sacc[i][j][r] - mn);
          sacc[i][j][r] = p;
          rs += p;
        }
#pragma unroll
        for (int off = 1; off < 16; off <<= 1) rs += __shfl_xor(rs, off);
        lrow[i][r] = lrow[i][r] * al + rs;
        mrow[i][r] = mn;
#pragma unroll
        for (int i2 = 0; i2 < 8; i2++) oacc[i][i2][r] *= al;
      }
    }

#pragma unroll
    for (int i = 0; i < 2; i++)
#pragma unroll
      for (int j = 0; j < 4; j++)
#pragma unroll
        for (int r = 0; r < 4; r++)
          Ps[(wv * 32 + i * 16 + quad * 4 + r) * 64 + j * 16 + l15] =
              __float2bfloat16(sacc[i][j][r]);
    __syncthreads();

#pragma unroll
    for (int kp = 0; kp < 2; kp++) {
      bf16x8 pa[2], vb[8];
#pragma unroll
      for (int i = 0; i < 2; i++)
        pa[i] = *(const bf16x8*)(Ps + (wv * 32 + i * 16 + l15) * 64 + kp * 32 + quad * 8);
#pragma unroll
      for (int i2 = 0; i2 < 8; i2++)
        vb[i2] = *(const bf16x8*)(Vts + (i2 * 16 + l15) * 64 + kp * 32 + quad * 8);
#pragma unroll
      for (int i = 0; i < 2; i++)
#pragma unroll
        for (int i2 = 0; i2 < 8; i2++)
          oacc[i][i2] = __builtin_amdgcn_mfma_f32_16x16x32_bf16(pa[i], vb[i2], oacc[i][i2], 0, 0, 0);
    }
  }

#pragma unroll
  for (int i = 0; i < 2; i++)
#pragma unroll
    for (int r = 0; r < 4; r++) {
      float inv = 1.0f / lrow[i][r];
      int row_g = bat * SEQ + qt * 128 + wv * 32 + i * 16 + quad * 4 + r;
#pragma unroll
      for (int i2 = 0; i2 < 8; i2++)
        aob[(size_t)row_g * ATTN_INNER + h * DH + i2 * 16 + l15] =
            __float2bfloat16(oacc[i][i2][r] * inv);
    }
}

// ---------------- host ----------------
extern "C" void kernel_launch(void* const* d_in, const int* in_sizes, int n_in,
                              void* d_out, int out_size, void* d_ws, size_t ws_size,
                              hipStream_t stream) {
  const float* x       = (const float*)d_in[0];
  const float* gamma   = (const float*)d_in[1];
  const float* beta    = (const float*)d_in[2];
  const float* w_fused = (const float*)d_in[3];
  const float* w_attn  = (const float*)d_in[4];
  const float* w_ff    = (const float*)d_in[5];
  float* out = (float*)d_out;
  char* ws = (char*)d_ws;

  size_t off = 0;
  auto alloc = [&](size_t bytes) {
    size_t o = off;
    off += (bytes + 255) & ~(size_t)255;
    return o;
  };
  __hip_bfloat16* hb   = (__hip_bfloat16*)(ws + alloc((size_t)ROWS * DIM * 2));
  __hip_bfloat16* wfbt = (__hip_bfloat16*)(ws + alloc((size_t)FUSED_N * DIM * 2));
  __hip_bfloat16* qkvb = (__hip_bfloat16*)(ws + alloc((size_t)ROWS * QKV_N * 2));
  __hip_bfloat16* gb   = (__hip_bfloat16*)(ws + alloc((size_t)ROWS * FF_INNER * 2));
  __hip_bfloat16* wat  = (__hip_bfloat16*)(ws + alloc((size_t)DIM * ATTN_INNER * 2));
  __hip_bfloat16* wfot = (__hip_bfloat16*)(ws + alloc((size_t)DIM * FF_INNER * 2));
  __hip_bfloat16* vt   = (__hip_bfloat16*)(ws + alloc((size_t)DH * ROWS * 2));
  __hip_bfloat16* aob  = (__hip_bfloat16*)(ws + alloc((size_t)ROWS * ATTN_INNER * 2));

  ln_kernel<<<ROWS, 256, 0, stream>>>(x, gamma, beta, hb);

  tcvt_kernel<<<dim3(FUSED_N / 64, DIM / 64), 256, 0, stream>>>(w_fused, wfbt, DIM, FUSED_N);
  tcvt_kernel<<<dim3(DIM / 64, ATTN_INNER / 64), 256, 0, stream>>>(w_attn, wat, ATTN_INNER, DIM);
  tcvt_kernel<<<dim3(DIM / 64, FF_INNER / 64), 256, 0, stream>>>(w_ff, wfot, FF_INNER, DIM);

  gemm_qkv<<<(QKV_N / 128) * (ROWS / 128), 256, 0, stream>>>(hb, wfbt, qkvb);

  rope_kernel<<<(ROWS * 17 * 64) / 256, 256, 0, stream>>>(qkvb);

  tbf16_kernel<<<dim3(DH / 64, ROWS / 64), 256, 0, stream>>>(qkvb + ATTN_INNER + DH, QKV_N, vt, ROWS, ROWS, DH);

  flash_kernel<<<512, 256, 0, stream>>>(qkvb, vt, aob);

  gemm_ff<<<(FF_INNER / 64) * (ROWS / 128), 256, 0, stream>>>(hb, wfbt, gb);

  gemm_out<<<(DIM / 128) * (ROWS / 128), 256, 0, stream>>>(aob, wat, gb, wfot, out);

  (void)in_sizes; (void)n_in; (void)out_size; (void)ws_size;
}

// Round 5
// 1131.270 us; speedup vs baseline: 1.0530x; 1.0194x over previous
//
#include <hip/hip_runtime.h>
#include <hip/hip_bf16.h>
#include <math.h>

#define DIM 2048
#define HEADS 16
#define DH 128
#define ATTN_INNER 2048
#define FF_INNER 8192
#define FUSED_N 18688
#define QKV_N 2304          // 2048 q + 128 k + 128 v
#define BATCH 2
#define SEQ 2048
#define ROWS (BATCH*SEQ)    // 4096

typedef __attribute__((ext_vector_type(8))) __bf16 bf16x8;
typedef __attribute__((ext_vector_type(4))) float f32x4;
typedef __attribute__((ext_vector_type(16))) float f32x16;

typedef __attribute__((address_space(1))) void* as1_void;
typedef __attribute__((address_space(3))) void* as3_void;

__device__ __forceinline__ void async16(const void* g, void* l) {
  __builtin_amdgcn_global_load_lds((as1_void)const_cast<void*>(g), (as3_void)l, 16, 0, 0);
}

// ---------------- LayerNorm: fp32 [rows][2048] -> bf16 ----------------
__global__ __launch_bounds__(256) void ln_kernel(const float* __restrict__ x,
                                                 const float* __restrict__ gamma,
                                                 const float* __restrict__ beta,
                                                 __hip_bfloat16* __restrict__ hb) {
  const int row = blockIdx.x;
  const int t = threadIdx.x;
  const float4* x4 = (const float4*)(x + (size_t)row * DIM);
  float4 a = x4[t];
  float4 c = x4[t + 256];
  float s  = a.x + a.y + a.z + a.w + c.x + c.y + c.z + c.w;
  float ss = a.x*a.x + a.y*a.y + a.z*a.z + a.w*a.w +
             c.x*c.x + c.y*c.y + c.z*c.z + c.w*c.w;
  for (int off = 32; off > 0; off >>= 1) {
    s  += __shfl_down(s, off);
    ss += __shfl_down(ss, off);
  }
  __shared__ float red[8];
  int wv = t >> 6, lane = t & 63;
  if (lane == 0) { red[wv] = s; red[wv + 4] = ss; }
  __syncthreads();
  s  = red[0] + red[1] + red[2] + red[3];
  ss = red[4] + red[5] + red[6] + red[7];
  float mu  = s * (1.0f / DIM);
  float var = ss * (1.0f / DIM) - mu * mu;
  float rs  = rsqrtf(var + 1e-5f);
  __hip_bfloat16* o = hb + (size_t)row * DIM;
  float v0[4] = {a.x, a.y, a.z, a.w};
  float v1[4] = {c.x, c.y, c.z, c.w};
#pragma unroll
  for (int i = 0; i < 4; i++) {
    int c0 = t * 4 + i;
    int c1 = 1024 + t * 4 + i;
    o[c0] = __float2bfloat16((v0[i] - mu) * rs * gamma[c0] + beta[c0]);
    o[c1] = __float2bfloat16((v1[i] - mu) * rs * gamma[c1] + beta[c1]);
  }
}

// ------------- transpose + fp32->bf16: src [R][C] -> dst [C][R] -------------
__global__ __launch_bounds__(256) void tcvt_kernel(const float* __restrict__ src,
                                                   __hip_bfloat16* __restrict__ dst,
                                                   int R, int C) {
  __shared__ float tile[64][65];
  const int cb = blockIdx.x * 64, rb = blockIdx.y * 64;
  const int t = threadIdx.x;
  const int lr = t >> 4, lc4 = (t & 15) * 4;
#pragma unroll
  for (int i = 0; i < 4; i++) {
    float4 v = *(const float4*)&src[(size_t)(rb + lr + i * 16) * C + cb + lc4];
    tile[lr + i * 16][lc4 + 0] = v.x;
    tile[lr + i * 16][lc4 + 1] = v.y;
    tile[lr + i * 16][lc4 + 2] = v.z;
    tile[lr + i * 16][lc4 + 3] = v.w;
  }
  __syncthreads();
  const int tcc = t & 31, trc = t >> 5;
#pragma unroll
  for (int i = 0; i < 8; i++) {
    int c = trc + i * 8;
    __hip_bfloat162 pk;
    pk.x = __float2bfloat16(tile[2 * tcc][c]);
    pk.y = __float2bfloat16(tile[2 * tcc + 1][c]);
    *(__hip_bfloat162*)&dst[(size_t)(cb + c) * R + rb + 2 * tcc] = pk;
  }
}

// ------------- transpose bf16: src [R][C] (ld) -> dst [C][R] (ldd) -------------
__global__ __launch_bounds__(256) void tbf16_kernel(const __hip_bfloat16* __restrict__ src, int lds_,
                                                    __hip_bfloat16* __restrict__ dst, int ldd,
                                                    int R, int C) {
  __shared__ __hip_bfloat16 tile[64][65];
  const int cb = blockIdx.x * 64, rb = blockIdx.y * 64;
  const int t = threadIdx.x;
  const int tc = t & 63, tr = t >> 6;
#pragma unroll
  for (int i = 0; i < 16; i++) {
    int r = tr + i * 4;
    tile[r][tc] = src[(size_t)(rb + r) * lds_ + cb + tc];
  }
  __syncthreads();
#pragma unroll
  for (int i = 0; i < 16; i++) {
    int c = tr + i * 4;
    dst[(size_t)(cb + c) * ldd + rb + tc] = tile[tc][c];
  }
}

// ---------------- RoPE in-place on qkv bf16 [4096][2304] ----------------
__global__ __launch_bounds__(256) void rope_kernel(__hip_bfloat16* __restrict__ qkv) {
  const size_t tid = (size_t)blockIdx.x * 256 + threadIdx.x;  // ROWS*17*64 total
  const int d = tid & 63;
  const int u = (tid >> 6) % 17;
  const int row = tid / (17 * 64);
  const int n = row & (SEQ - 1);
  size_t base = (size_t)row * QKV_N + (u < 16 ? u * DH : ATTN_INNER);
  float inv = powf(10000.0f, -(float)d * (1.0f / 64.0f));
  float th = (float)n * inv;
  float cs = cosf(th), sn = sinf(th);
  float a = __bfloat162float(qkv[base + d]);
  float b = __bfloat162float(qkv[base + d + 64]);
  qkv[base + d]      = __float2bfloat16(a * cs - b * sn);
  qkv[base + d + 64] = __float2bfloat16(b * cs + a * sn);
}

// XOR-swizzled LDS tile, 128 rows x 32 cols bf16 (64 B row = 4 x 16B blocks).
// Element (row, logical block l) lives at physical block l ^ ((row>>1)&3).
// Key bits [2:1] of row are independent of row parity -> fragment reads hit
// the 8-way b128 structural floor (all 32 banks covered).
// Staging: lane's LDS slot fixed (row = q*16 + (lane>>2), phys blk = lane&3);
// global col block = (lane&3) ^ ((lane>>3)&3).

// ---------------- qkv GEMM (32x32x16): C[4096][2304] = hb @ wfbt[0:2304]^T
__global__ __launch_bounds__(256, 3) void gemm_qkv(const __hip_bfloat16* __restrict__ A,
                                                   const __hip_bfloat16* __restrict__ Bt,
                                                   __hip_bfloat16* __restrict__ C) {
  __shared__ __hip_bfloat16 As[2][128 * 32];
  __shared__ __hip_bfloat16 Bs[2][128 * 32];
  const int tid = threadIdx.x;
  const int wv = tid >> 6, lane = tid & 63;
  const int l31 = lane & 31, khalf = lane >> 5;
  const int rx = (l31 >> 1) & 3;                  // xor key for fragment reads
  const int pid = blockIdx.x;                     // grid 576
  const int xcd = pid & 7, lid = pid >> 3;        // lid in [0,72)
  const int m0 = (xcd * 4 + (lid & 3)) * 128;
  const int n0 = (lid >> 2) * 128;
  const int wm = (wv >> 1) * 64, wn = (wv & 1) * 64;
  const int srow = lane >> 2;
  const int scol = (((lane & 3) ^ ((lane >> 3) & 3)) * 8);

  f32x16 acc[2][2] = {};
  for (int k0 = 0; k0 < DIM; k0 += 64) {
#pragma unroll
    for (int h = 0; h < 2; h++)
#pragma unroll
      for (int j = 0; j < 2; j++) {
        int q = wv * 2 + j;
        int row = q * 16 + srow;
        async16(A  + (size_t)(m0 + row) * DIM + k0 + h * 32 + scol, &As[h][q * 512]);
        async16(Bt + (size_t)(n0 + row) * DIM + k0 + h * 32 + scol, &Bs[h][q * 512]);
      }
    __syncthreads();
#pragma unroll
    for (int h = 0; h < 2; h++)
#pragma unroll
      for (int kk = 0; kk < 2; kk++) {
        const int blk = (kk * 2 + khalf) ^ rx;
        bf16x8 af[2], bfr[2];
#pragma unroll
        for (int i = 0; i < 2; i++)
          af[i] = *(const bf16x8*)(&As[h][(wm + i * 32 + l31) * 32 + blk * 8]);
#pragma unroll
        for (int j = 0; j < 2; j++)
          bfr[j] = *(const bf16x8*)(&Bs[h][(wn + j * 32 + l31) * 32 + blk * 8]);
#pragma unroll
        for (int i = 0; i < 2; i++)
#pragma unroll
          for (int j = 0; j < 2; j++)
            acc[i][j] = __builtin_amdgcn_mfma_f32_32x32x16_bf16(af[i], bfr[j], acc[i][j], 0, 0, 0);
      }
    __syncthreads();
  }
#pragma unroll
  for (int i = 0; i < 2; i++)
#pragma unroll
    for (int j = 0; j < 2; j++) {
      int colg = n0 + wn + j * 32 + l31;
#pragma unroll
      for (int r = 0; r < 16; r++) {
        int rowg = m0 + wm + i * 32 + (r & 3) + 4 * khalf + 8 * (r >> 2);
        C[(size_t)rowg * QKV_N + colg] = __float2bfloat16(acc[i][j][r]);
      }
    }
}

// ---------------- merged FF GEMM (32x32x16): gb = silu(h@Wg^T) * (h@Wx^T)
__global__ __launch_bounds__(256, 3) void gemm_ff(const __hip_bfloat16* __restrict__ A,
                                                  const __hip_bfloat16* __restrict__ W,
                                                  __hip_bfloat16* __restrict__ G) {
  __shared__ __hip_bfloat16 As[2][128 * 32];
  __shared__ __hip_bfloat16 Bs[2][128 * 32];
  const int tid = threadIdx.x;
  const int wv = tid >> 6, lane = tid & 63;
  const int l31 = lane & 31, khalf = lane >> 5;
  const int rx = (l31 >> 1) & 3;
  const int pid = blockIdx.x;                     // grid 4096
  const int xcd = pid & 7, lid = pid >> 3;        // lid in [0,512)
  const int m0 = (xcd * 4 + (lid & 3)) * 128;
  const int n0 = (lid >> 2) * 64;                 // n-tile 0..127
  const int wm = (wv >> 1) * 64, wn2 = (wv & 1) * 32;
  const int srow = lane >> 2;
  const int scol = (((lane & 3) ^ ((lane >> 3) & 3)) * 8);

  f32x16 ax[2] = {};
  f32x16 ag[2] = {};
  for (int k0 = 0; k0 < DIM; k0 += 64) {
#pragma unroll
    for (int h = 0; h < 2; h++)
#pragma unroll
      for (int j = 0; j < 2; j++) {
        int q = wv * 2 + j;
        int row = q * 16 + srow;
        async16(A + (size_t)(m0 + row) * DIM + k0 + h * 32 + scol, &As[h][q * 512]);
        int wr = (row < 64) ? (QKV_N + n0 + row)
                            : (QKV_N + FF_INNER + n0 + row - 64);
        async16(W + (size_t)wr * DIM + k0 + h * 32 + scol, &Bs[h][q * 512]);
      }
    __syncthreads();
#pragma unroll
    for (int h = 0; h < 2; h++)
#pragma unroll
      for (int kk = 0; kk < 2; kk++) {
        const int blk = (kk * 2 + khalf) ^ rx;
        bf16x8 af[2], bx, bg;
#pragma unroll
        for (int i = 0; i < 2; i++)
          af[i] = *(const bf16x8*)(&As[h][(wm + i * 32 + l31) * 32 + blk * 8]);
        bx = *(const bf16x8*)(&Bs[h][(wn2 + l31) * 32 + blk * 8]);
        bg = *(const bf16x8*)(&Bs[h][(64 + wn2 + l31) * 32 + blk * 8]);
#pragma unroll
        for (int i = 0; i < 2; i++) {
          ax[i] = __builtin_amdgcn_mfma_f32_32x32x16_bf16(af[i], bx, ax[i], 0, 0, 0);
          ag[i] = __builtin_amdgcn_mfma_f32_32x32x16_bf16(af[i], bg, ag[i], 0, 0, 0);
        }
      }
    __syncthreads();
  }
#pragma unroll
  for (int i = 0; i < 2; i++) {
    int colg = n0 + wn2 + l31;
#pragma unroll
    for (int r = 0; r < 16; r++) {
      int rowg = m0 + wm + i * 32 + (r & 3) + 4 * khalf + 8 * (r >> 2);
      float xv = ax[i][r];
      float gv = ag[i][r];
      float o = gv / (1.0f + expf(-gv)) * xv;
      G[(size_t)rowg * FF_INNER + colg] = __float2bfloat16(o);
    }
  }
}

// ---------------- merged output GEMM (32x32x16): out = aob@wat^T + gb@wfot^T
__global__ __launch_bounds__(256, 3) void gemm_out(const __hip_bfloat16* __restrict__ A0,
                                                   const __hip_bfloat16* __restrict__ B0,
                                                   const __hip_bfloat16* __restrict__ A1,
                                                   const __hip_bfloat16* __restrict__ B1,
                                                   float* __restrict__ C) {
  __shared__ __hip_bfloat16 As[2][128 * 32];
  __shared__ __hip_bfloat16 Bs[2][128 * 32];
  const int tid = threadIdx.x;
  const int wv = tid >> 6, lane = tid & 63;
  const int l31 = lane & 31, khalf = lane >> 5;
  const int rx = (l31 >> 1) & 3;
  const int pid = blockIdx.x;                     // grid 512
  const int xcd = pid & 7, lid = pid >> 3;        // lid in [0,64)
  const int m0 = (xcd * 4 + (lid & 3)) * 128;
  const int n0 = (lid >> 2) * 128;                // n-tile 0..15
  const int wm = (wv >> 1) * 64, wn = (wv & 1) * 64;
  const int srow = lane >> 2;
  const int scol = (((lane & 3) ^ ((lane >> 3) & 3)) * 8);

  f32x16 acc[2][2] = {};
  for (int p = 0; p < 2; p++) {
    const __hip_bfloat16* A = p ? A1 : A0;
    const __hip_bfloat16* B = p ? B1 : B0;
    const int K = p ? FF_INNER : ATTN_INNER;
    for (int k0 = 0; k0 < K; k0 += 64) {
#pragma unroll
      for (int h = 0; h < 2; h++)
#pragma unroll
        for (int j = 0; j < 2; j++) {
          int q = wv * 2 + j;
          int row = q * 16 + srow;
          async16(A + (size_t)(m0 + row) * K + k0 + h * 32 + scol, &As[h][q * 512]);
          async16(B + (size_t)(n0 + row) * K + k0 + h * 32 + scol, &Bs[h][q * 512]);
        }
      __syncthreads();
#pragma unroll
      for (int h = 0; h < 2; h++)
#pragma unroll
        for (int kk = 0; kk < 2; kk++) {
          const int blk = (kk * 2 + khalf) ^ rx;
          bf16x8 af[2], bfr[2];
#pragma unroll
          for (int i = 0; i < 2; i++)
            af[i] = *(const bf16x8*)(&As[h][(wm + i * 32 + l31) * 32 + blk * 8]);
#pragma unroll
          for (int j = 0; j < 2; j++)
            bfr[j] = *(const bf16x8*)(&Bs[h][(wn + j * 32 + l31) * 32 + blk * 8]);
#pragma unroll
          for (int i = 0; i < 2; i++)
#pragma unroll
            for (int j = 0; j < 2; j++)
              acc[i][j] = __builtin_amdgcn_mfma_f32_32x32x16_bf16(af[i], bfr[j], acc[i][j], 0, 0, 0);
        }
      __syncthreads();
    }
  }
#pragma unroll
  for (int i = 0; i < 2; i++)
#pragma unroll
    for (int j = 0; j < 2; j++) {
      int colg = n0 + wn + j * 32 + l31;
#pragma unroll
      for (int r = 0; r < 16; r++) {
        int rowg = m0 + wm + i * 32 + (r & 3) + 4 * khalf + 8 * (r >> 2);
        C[(size_t)rowg * DIM + colg] = acc[i][j][r];
      }
    }
}

// ---------------- Flash attention (multi-query, causal) ----------------
__global__ __launch_bounds__(256) void flash_kernel(const __hip_bfloat16* __restrict__ qkv,
                                                    const __hip_bfloat16* __restrict__ vt,
                                                    __hip_bfloat16* __restrict__ aob) {
  __shared__ __hip_bfloat16 Qs[128 * 128];
  __shared__ __hip_bfloat16 Ks[64 * 128];
  __shared__ __hip_bfloat16 Vts[128 * 64];
  __shared__ __hip_bfloat16 Ps[128 * 64];

  const int blk = blockIdx.x;           // qi*32 + bh
  const int bh = blk & 31;
  const int qi = blk >> 5;
  const int qt = (qi & 1) ? (qi >> 1) : (15 - (qi >> 1));
  const int bat = bh >> 4, h = bh & 15;

  const int tid = threadIdx.x;
  const int wv = tid >> 6, lane = tid & 63;
  const int quad = lane >> 4, l15 = lane & 15;
  const float scale = 0.08838834764831845f;

#pragma unroll
  for (int j = 0; j < 8; j++) {
    int is = wv * 8 + j;
    int e = is * 512 + lane * 8;
    int r = e >> 7, c = e & 127;
    async16(qkv + (size_t)(bat * SEQ + qt * 128 + r) * QKV_N + h * DH + c, Qs + is * 512);
  }

  f32x4 oacc[2][8];
#pragma unroll
  for (int i = 0; i < 2; i++)
#pragma unroll
    for (int j = 0; j < 8; j++) oacc[i][j] = (f32x4){0.f, 0.f, 0.f, 0.f};
  float mrow[2][4], lrow[2][4];
#pragma unroll
  for (int i = 0; i < 2; i++)
#pragma unroll
    for (int r = 0; r < 4; r++) { mrow[i][r] = -INFINITY; lrow[i][r] = 0.f; }

  const int jt_max = 2 * qt + 1;
  for (int jt = 0; jt <= jt_max; jt++) {
    __syncthreads();
#pragma unroll
    for (int j = 0; j < 4; j++) {
      int is = wv * 4 + j;
      int e = is * 512 + lane * 8;
      { int r = e >> 7, c = e & 127;
        async16(qkv + (size_t)(bat * SEQ + jt * 64 + r) * QKV_N + ATTN_INNER + c, Ks + is * 512); }
      { int d = e >> 6, jc = e & 63;
        async16(vt + (size_t)d * ROWS + bat * SEQ + jt * 64 + jc, Vts + is * 512); }
    }
    __syncthreads();

    f32x4 sacc[2][4];
#pragma unroll
    for (int i = 0; i < 2; i++)
#pragma unroll
      for (int j = 0; j < 4; j++) sacc[i][j] = (f32x4){0.f, 0.f, 0.f, 0.f};
#pragma unroll
    for (int kq = 0; kq < 4; kq++) {
      bf16x8 qa[2], kb[4];
#pragma unroll
      for (int i = 0; i < 2; i++)
        qa[i] = *(const bf16x8*)(Qs + (wv * 32 + i * 16 + l15) * 128 + kq * 32 + quad * 8);
#pragma unroll
      for (int j = 0; j < 4; j++)
        kb[j] = *(const bf16x8*)(Ks + (j * 16 + l15) * 128 + kq * 32 + quad * 8);
#pragma unroll
      for (int i = 0; i < 2; i++)
#pragma unroll
        for (int j = 0; j < 4; j++)
          sacc[i][j] = __builtin_amdgcn_mfma_f32_16x16x32_bf16(qa[i], kb[j], sacc[i][j], 0, 0, 0);
    }

#pragma unroll
    for (int i = 0; i < 2; i++) {
#pragma unroll
      for (int r = 0; r < 4; r++) {
        int row_g = qt * 128 + wv * 32 + i * 16 + quad * 4 + r;
        float mt = -INFINITY;
#pragma unroll
        for (int j = 0; j < 4; j++) {
          int col_g = jt * 64 + j * 16 + l15;
          float sv = sacc[i][j][r] * scale;
          if (col_g > row_g) sv = -INFINITY;
          sacc[i][j][r] = sv;
          mt = fmaxf(mt, sv);
        }
#pragma unroll
        for (int off = 1; off < 16; off <<= 1) mt = fmaxf(mt, __shfl_xor(mt, off));
        float mn = fmaxf(mrow[i][r], mt);
        float al = expf(mrow[i][r] - mn);
        float rs = 0.f;
#pragma unroll
        for (int j = 0; j < 4; j++) {
          float p = expf(sacc[i][j][r] - mn);
          sacc[i][j][r] = p;
          rs += p;
        }
#pragma unroll
        for (int off = 1; off < 16; off <<= 1) rs += __shfl_xor(rs, off);
        lrow[i][r] = lrow[i][r] * al + rs;
        mrow[i][r] = mn;
#pragma unroll
        for (int i2 = 0; i2 < 8; i2++) oacc[i][i2][r] *= al;
      }
    }

#pragma unroll
    for (int i = 0; i < 2; i++)
#pragma unroll
      for (int j = 0; j < 4; j++)
#pragma unroll
        for (int r = 0; r < 4; r++)
          Ps[(wv * 32 + i * 16 + quad * 4 + r) * 64 + j * 16 + l15] =
              __float2bfloat16(sacc[i][j][r]);
    __syncthreads();

#pragma unroll
    for (int kp = 0; kp < 2; kp++) {
      bf16x8 pa[2], vb[8];
#pragma unroll
      for (int i = 0; i < 2; i++)
        pa[i] = *(const bf16x8*)(Ps + (wv * 32 + i * 16 + l15) * 64 + kp * 32 + quad * 8);
#pragma unroll
      for (int i2 = 0; i2 < 8; i2++)
        vb[i2] = *(const bf16x8*)(Vts + (i2 * 16 + l15) * 64 + kp * 32 + quad * 8);
#pragma unroll
      for (int i = 0; i < 2; i++)
#pragma unroll
        for (int i2 = 0; i2 < 8; i2++)
          oacc[i][i2] = __builtin_amdgcn_mfma_f32_16x16x32_bf16(pa[i], vb[i2], oacc[i][i2], 0, 0, 0);
    }
  }

#pragma unroll
  for (int i = 0; i < 2; i++)
#pragma unroll
    for (int r = 0; r < 4; r++) {
      float inv = 1.0f / lrow[i][r];
      int row_g = bat * SEQ + qt * 128 + wv * 32 + i * 16 + quad * 4 + r;
#pragma unroll
      for (int i2 = 0; i2 < 8; i2++)
        aob[(size_t)row_g * ATTN_INNER + h * DH + i2 * 16 + l15] =
            __float2bfloat16(oacc[i][i2][r] * inv);
    }
}

// ---------------- host ----------------
extern "C" void kernel_launch(void* const* d_in, const int* in_sizes, int n_in,
                              void* d_out, int out_size, void* d_ws, size_t ws_size,
                              hipStream_t stream) {
  const float* x       = (const float*)d_in[0];
  const float* gamma   = (const float*)d_in[1];
  const float* beta    = (const float*)d_in[2];
  const float* w_fused = (const float*)d_in[3];
  const float* w_attn  = (const float*)d_in[4];
  const float* w_ff    = (const float*)d_in[5];
  float* out = (float*)d_out;
  char* ws = (char*)d_ws;

  size_t off = 0;
  auto alloc = [&](size_t bytes) {
    size_t o = off;
    off += (bytes + 255) & ~(size_t)255;
    return o;
  };
  __hip_bfloat16* hb   = (__hip_bfloat16*)(ws + alloc((size_t)ROWS * DIM * 2));
  __hip_bfloat16* wfbt = (__hip_bfloat16*)(ws + alloc((size_t)FUSED_N * DIM * 2));
  __hip_bfloat16* qkvb = (__hip_bfloat16*)(ws + alloc((size_t)ROWS * QKV_N * 2));
  __hip_bfloat16* gb   = (__hip_bfloat16*)(ws + alloc((size_t)ROWS * FF_INNER * 2));
  __hip_bfloat16* wat  = (__hip_bfloat16*)(ws + alloc((size_t)DIM * ATTN_INNER * 2));
  __hip_bfloat16* wfot = (__hip_bfloat16*)(ws + alloc((size_t)DIM * FF_INNER * 2));
  __hip_bfloat16* vt   = (__hip_bfloat16*)(ws + alloc((size_t)DH * ROWS * 2));
  __hip_bfloat16* aob  = (__hip_bfloat16*)(ws + alloc((size_t)ROWS * ATTN_INNER * 2));

  ln_kernel<<<ROWS, 256, 0, stream>>>(x, gamma, beta, hb);

  tcvt_kernel<<<dim3(FUSED_N / 64, DIM / 64), 256, 0, stream>>>(w_fused, wfbt, DIM, FUSED_N);
  tcvt_kernel<<<dim3(DIM / 64, ATTN_INNER / 64), 256, 0, stream>>>(w_attn, wat, ATTN_INNER, DIM);
  tcvt_kernel<<<dim3(DIM / 64, FF_INNER / 64), 256, 0, stream>>>(w_ff, wfot, FF_INNER, DIM);

  gemm_qkv<<<(QKV_N / 128) * (ROWS / 128), 256, 0, stream>>>(hb, wfbt, qkvb);

  rope_kernel<<<(ROWS * 17 * 64) / 256, 256, 0, stream>>>(qkvb);

  tbf16_kernel<<<dim3(DH / 64, ROWS / 64), 256, 0, stream>>>(qkvb + ATTN_INNER + DH, QKV_N, vt, ROWS, ROWS, DH);

  flash_kernel<<<512, 256, 0, stream>>>(qkvb, vt, aob);

  gemm_ff<<<(FF_INNER / 64) * (ROWS / 128), 256, 0, stream>>>(hb, wfbt, gb);

  gemm_out<<<(DIM / 128) * (ROWS / 128), 256, 0, stream>>>(aob, wat, gb, wfot, out);

  (void)in_sizes; (void)n_in; (void)out_size; (void)ws_size;
}